// Round 4
// baseline (364.851 us; speedup 1.0000x reference)
//
#include <hip/hip_runtime.h>
#include <stdint.h>

typedef int int32x4 __attribute__((ext_vector_type(4)));

constexpr int K_DIM = 4096;   // D_IN
constexpr int N_DIM = 4096;   // D_OUT
constexpr float QMAXF = 127.0f;

// ---------------------------------------------------------------------------
// Kernel 1: per-token dynamic absmax quantization
// ---------------------------------------------------------------------------
__global__ __launch_bounds__(256) void quant_rows(const float* __restrict__ x,
                                                  int8_t* __restrict__ q,
                                                  float* __restrict__ scales) {
    const int row = blockIdx.x;
    const int tid = threadIdx.x;
    const size_t base = (size_t)row * K_DIM;

    const float4* xv = reinterpret_cast<const float4*>(x + base);
    float4 v[4];
#pragma unroll
    for (int i = 0; i < 4; ++i) v[i] = xv[tid + 256 * i];

    float m = 0.0f;
#pragma unroll
    for (int i = 0; i < 4; ++i)
        m = fmaxf(m, fmaxf(fmaxf(fabsf(v[i].x), fabsf(v[i].y)),
                           fmaxf(fabsf(v[i].z), fabsf(v[i].w))));
#pragma unroll
    for (int off = 32; off > 0; off >>= 1) m = fmaxf(m, __shfl_xor(m, off));

    __shared__ float wmax[4];
    if ((tid & 63) == 0) wmax[tid >> 6] = m;
    __syncthreads();
    const float am = fmaxf(fmaxf(wmax[0], wmax[1]), fmaxf(wmax[2], wmax[3]));
    const float scale = fmaxf(am * (1.0f / 127.0f), 1e-8f);
    if (tid == 0) scales[row] = scale;
    const float inv = 1.0f / scale;

    int* qw = reinterpret_cast<int*>(q + base);
#pragma unroll
    for (int i = 0; i < 4; ++i) {
        float f0 = fminf(QMAXF, fmaxf(-QMAXF, rintf(v[i].x * inv)));
        float f1 = fminf(QMAXF, fmaxf(-QMAXF, rintf(v[i].y * inv)));
        float f2 = fminf(QMAXF, fmaxf(-QMAXF, rintf(v[i].z * inv)));
        float f3 = fminf(QMAXF, fmaxf(-QMAXF, rintf(v[i].w * inv)));
        int b0 = ((int)f0) & 255, b1 = ((int)f1) & 255;
        int b2 = ((int)f2) & 255, b3 = ((int)f3) & 255;
        qw[tid + 256 * i] = b0 | (b1 << 8) | (b2 << 16) | (b3 << 24);
    }
}

// ---------------------------------------------------------------------------
// Kernel 2: pack int32 weight buffer -> int8
// ---------------------------------------------------------------------------
__global__ __launch_bounds__(256) void pack_w(const int* __restrict__ w,
                                              int8_t* __restrict__ w8) {
    const int idx = blockIdx.x * 256 + threadIdx.x;
    const int4 v = reinterpret_cast<const int4*>(w)[idx];
    int packed = (v.x & 255) | ((v.y & 255) << 8) | ((v.z & 255) << 16) | ((v.w & 255) << 24);
    reinterpret_cast<int*>(w8)[idx] = packed;
}

// ---------------------------------------------------------------------------
// Kernel 3: int8 GEMM, flatmm-style. 256x256 tile, BK=64, 8 waves (2Mx4N).
//  - A fragments: direct global->VGPR loads (L1/L2-resident q), reg-dbuf'd.
//    Each load is 16 rows x 64B = 16 full cache lines (line-coalesced).
//  - B: LDS 3-deep ring (48 KB), global_load_lds staging, XOR swizzle (T2).
//  - 1 barrier + counted vmcnt per K-tile (T4); setprio on MFMA (T5).
// vmcnt proof: body t issues A(t+1)x8 then B(t+2)x2 (GLL). End-of-tile
// vmcnt(10) allows exactly those 10 => B(t+1) landed before its ds_read at
// t+1 (barrier makes it block-wide). Compiler's own wait before MFMA(t)
// covers A(t). WAR on ring slot: GLL(t+2) -> slot (t+2)%3 = (t-1)%3, whose
// last ds_read finished before end-of-(t-1) barrier. Never drains to 0.
// ---------------------------------------------------------------------------
constexpr int BM = 256, BN = 256, BK = 64;
constexpr int NT = K_DIM / BK;     // 64 K-tiles

#define GLL(src, dst)                                                          \
    __builtin_amdgcn_global_load_lds(                                          \
        (const __attribute__((address_space(1))) unsigned int*)(src),          \
        (__attribute__((address_space(3))) unsigned int*)(dst), 16, 0, 0)

#define MFMA_I8(a, b, c) __builtin_amdgcn_mfma_i32_16x16x64_i8((a), (b), (c), 0, 0, 0)

__global__ __launch_bounds__(512, 2) void w8a8_gemm256(
        const int8_t* __restrict__ A, const int8_t* __restrict__ B,
        const float* __restrict__ asc, const float* __restrict__ wsc,
        float* __restrict__ C, int M) {
    __shared__ int8_t Bs[3][BM][BK];          // 48 KB

    const int tid  = threadIdx.x;
    const int lane = tid & 63;
    const int wave = tid >> 6;

    // XCD-aware bijective swizzle (nwg = 512, divisible by 8)
    const int nwg = gridDim.x;
    const int bid = blockIdx.x;
    const int swz = (bid & 7) * (nwg >> 3) + (bid >> 3);
    const int NB  = N_DIM / BN;               // 16
    const int brow = (swz / NB) * BM;
    const int bcol = (swz % NB) * BN;

    const int wm = wave >> 2;                 // 0..1  (M half)
    const int wn = wave & 3;                  // 0..3  (N quarter)

    const int l15 = lane & 15;
    const int ls  = lane >> 4;

    // ---- B staging: seg s -> row s>>2, LDS slot s&3, global granule swizzled
    const int s0 = tid, s1 = tid + 512;
    const int r0s = s0 >> 2, g0 = (s0 & 3) ^ ((r0s >> 1) & 3);
    const int r1s = s1 >> 2, g1 = (s1 & 3) ^ ((r1s >> 1) & 3);
    const int8_t* gB0 = B + (size_t)(bcol + r0s) * K_DIM + g0 * 16;
    const int8_t* gB1 = B + (size_t)(bcol + r1s) * K_DIM + g1 * 16;
    const int segb0 = wave * 1024;            // wave-uniform LDS base (HW adds lane*16)
    const int segb1 = segb0 + 8192;

    // ---- B compute-side swizzled LDS offset
    const int rB  = wn * 64 + l15;
    const int offB = rB * BK + ((ls ^ ((rB >> 1) & 3)) * 16);

    // ---- A per-lane base: row = brow + wm*128 + l15 (+ mi*16), col = ls*16 (+ t*64)
    const int8_t* aptr = A + (size_t)(brow + wm * 128 + l15) * K_DIM + ls * 16;

    int32x4 acc[8][4];
#pragma unroll
    for (int i = 0; i < 8; ++i)
#pragma unroll
        for (int j = 0; j < 4; ++j) acc[i][j] = (int32x4){0, 0, 0, 0};

    int32x4 av0[8], av1[8];

    // ---- prologue: A(0) -> av0; stage B(0), B(1)
#pragma unroll
    for (int mi = 0; mi < 8; ++mi)
        av0[mi] = *(const int32x4*)(aptr + (size_t)mi * 16 * K_DIM);
    GLL(gB0, &Bs[0][0][0] + segb0);
    GLL(gB1, &Bs[0][0][0] + segb1);
    GLL(gB0 + 64, &Bs[1][0][0] + segb0);
    GLL(gB1 + 64, &Bs[1][0][0] + segb1);
    asm volatile("s_waitcnt vmcnt(2)" ::: "memory");   // A(0), B(0) landed
    __builtin_amdgcn_s_barrier();

#define BODY_FULL(T, CUR, NXT)                                                 \
    {                                                                          \
        const int8_t* ap = aptr + ((T) + 1) * 64;                              \
        _Pragma("unroll")                                                      \
        for (int mi = 0; mi < 8; ++mi)                                         \
            NXT[mi] = *(const int32x4*)(ap + (size_t)mi * 16 * K_DIM);         \
        int8_t* lB = &Bs[((T) + 2) % 3][0][0];                                 \
        GLL(gB0 + ((T) + 2) * 64, lB + segb0);                                 \
        GLL(gB1 + ((T) + 2) * 64, lB + segb1);                                 \
        const int8_t* bbuf = &Bs[(T) % 3][0][0];                               \
        int32x4 bf[4];                                                         \
        _Pragma("unroll")                                                      \
        for (int ni = 0; ni < 4; ++ni)                                         \
            bf[ni] = *(const int32x4*)(bbuf + offB + ni * 1024);               \
        __builtin_amdgcn_s_setprio(1);                                         \
        _Pragma("unroll")                                                      \
        for (int mi = 0; mi < 8; ++mi)                                         \
            _Pragma("unroll")                                                  \
            for (int ni = 0; ni < 4; ++ni)                                     \
                acc[mi][ni] = MFMA_I8(CUR[mi], bf[ni], acc[mi][ni]);           \
        __builtin_amdgcn_s_setprio(0);                                         \
        asm volatile("s_waitcnt vmcnt(10)" ::: "memory");                      \
        __builtin_amdgcn_s_barrier();                                          \
    }

    // ---- main loop: tiles 0 .. NT-3 ----
    for (int t = 0; t < NT - 2; t += 2) {
        BODY_FULL(t,     av0, av1);
        BODY_FULL(t + 1, av1, av0);
    }

    // ---- tail tile NT-2 (issue A(NT-1), no GLL, vmcnt(8)) ----
    {
        const int8_t* ap = aptr + (NT - 1) * 64;
#pragma unroll
        for (int mi = 0; mi < 8; ++mi)
            av1[mi] = *(const int32x4*)(ap + (size_t)mi * 16 * K_DIM);
        const int8_t* bbuf = &Bs[(NT - 2) % 3][0][0];
        int32x4 bf[4];
#pragma unroll
        for (int ni = 0; ni < 4; ++ni)
            bf[ni] = *(const int32x4*)(bbuf + offB + ni * 1024);
        __builtin_amdgcn_s_setprio(1);
#pragma unroll
        for (int mi = 0; mi < 8; ++mi)
#pragma unroll
            for (int ni = 0; ni < 4; ++ni)
                acc[mi][ni] = MFMA_I8(av0[mi], bf[ni], acc[mi][ni]);
        __builtin_amdgcn_s_setprio(0);
        asm volatile("s_waitcnt vmcnt(8)" ::: "memory");   // B(NT-1) landed
        __builtin_amdgcn_s_barrier();
    }
    // ---- tail tile NT-1 ----
    {
        const int8_t* bbuf = &Bs[(NT - 1) % 3][0][0];
        int32x4 bf[4];
#pragma unroll
        for (int ni = 0; ni < 4; ++ni)
            bf[ni] = *(const int32x4*)(bbuf + offB + ni * 1024);
        __builtin_amdgcn_s_setprio(1);
#pragma unroll
        for (int mi = 0; mi < 8; ++mi)
#pragma unroll
            for (int ni = 0; ni < 4; ++ni)
                acc[mi][ni] = MFMA_I8(av1[mi], bf[ni], acc[mi][ni]);
        __builtin_amdgcn_s_setprio(0);
    }

    // ---- epilogue: dequant + fp16-round; C/D: col=lane&15, row=(lane>>4)*4+reg
    const int c0  = lane & 15;
    const int rr0 = (lane >> 4) * 4;
#pragma unroll
    for (int ni = 0; ni < 4; ++ni) {
        const int col = bcol + wn * 64 + ni * 16 + c0;
        const float ws = wsc[col];
#pragma unroll
        for (int mi = 0; mi < 8; ++mi) {
            const int rowb = brow + wm * 128 + mi * 16 + rr0;
#pragma unroll
            for (int r = 0; r < 4; ++r) {
                const int row = rowb + r;
                float o = (float)acc[mi][ni][r] * asc[row] * ws;
                o = (float)(_Float16)o;   // emulate reference's fp16 cast
                C[(size_t)row * N_DIM + col] = o;
            }
        }
    }
}

// ---------------------------------------------------------------------------
extern "C" void kernel_launch(void* const* d_in, const int* in_sizes, int n_in,
                              void* d_out, int out_size, void* d_ws, size_t ws_size,
                              hipStream_t stream) {
    const float* x   = (const float*)d_in[0];   // [M][K], fp16-valued f32
    const int*   w   = (const int*)d_in[1];     // [N][K] int32 (int8-valued)
    const float* wsc = (const float*)d_in[2];   // [N]
    float* out = (float*)d_out;                 // [M][N] (fp16-valued f32)

    const int K = K_DIM;
    const int M = in_sizes[0] / K;              // 8192
    const int N = N_DIM;

    int8_t* q   = (int8_t*)d_ws;                               // M*K  = 32 MB
    int8_t* w8  = (int8_t*)d_ws + (size_t)M * K;               // N*K  = 16 MB
    float*  asc = (float*)((char*)d_ws + (size_t)M * K + (size_t)N * K);

    quant_rows<<<M, 256, 0, stream>>>(x, q, asc);
    pack_w<<<(N * (K / 4)) / 256, 256, 0, stream>>>(w, w8);
    const int grid = (M / BM) * (N / BN);       // 512
    w8a8_gemm256<<<grid, 512, 0, stream>>>(q, w8, asc, wsc, out, M);
}

// Round 5
// 186.166 us; speedup vs baseline: 1.9598x; 1.9598x over previous
//
#include <hip/hip_runtime.h>
#include <stdint.h>

typedef int int32x4 __attribute__((ext_vector_type(4)));

constexpr int K_DIM = 4096;   // D_IN
constexpr int N_DIM = 4096;   // D_OUT
constexpr float QMAXF = 127.0f;

// ---------------------------------------------------------------------------
// Kernel 1: per-token dynamic absmax quantization
// ---------------------------------------------------------------------------
__global__ __launch_bounds__(256) void quant_rows(const float* __restrict__ x,
                                                  int8_t* __restrict__ q,
                                                  float* __restrict__ scales) {
    const int row = blockIdx.x;
    const int tid = threadIdx.x;
    const size_t base = (size_t)row * K_DIM;

    const float4* xv = reinterpret_cast<const float4*>(x + base);
    float4 v[4];
#pragma unroll
    for (int i = 0; i < 4; ++i) v[i] = xv[tid + 256 * i];

    float m = 0.0f;
#pragma unroll
    for (int i = 0; i < 4; ++i)
        m = fmaxf(m, fmaxf(fmaxf(fabsf(v[i].x), fabsf(v[i].y)),
                           fmaxf(fabsf(v[i].z), fabsf(v[i].w))));
#pragma unroll
    for (int off = 32; off > 0; off >>= 1) m = fmaxf(m, __shfl_xor(m, off));

    __shared__ float wmax[4];
    if ((tid & 63) == 0) wmax[tid >> 6] = m;
    __syncthreads();
    const float am = fmaxf(fmaxf(wmax[0], wmax[1]), fmaxf(wmax[2], wmax[3]));
    const float scale = fmaxf(am * (1.0f / 127.0f), 1e-8f);
    if (tid == 0) scales[row] = scale;
    const float inv = 1.0f / scale;

    int* qw = reinterpret_cast<int*>(q + base);
#pragma unroll
    for (int i = 0; i < 4; ++i) {
        float f0 = fminf(QMAXF, fmaxf(-QMAXF, rintf(v[i].x * inv)));
        float f1 = fminf(QMAXF, fmaxf(-QMAXF, rintf(v[i].y * inv)));
        float f2 = fminf(QMAXF, fmaxf(-QMAXF, rintf(v[i].z * inv)));
        float f3 = fminf(QMAXF, fmaxf(-QMAXF, rintf(v[i].w * inv)));
        int b0 = ((int)f0) & 255, b1 = ((int)f1) & 255;
        int b2 = ((int)f2) & 255, b3 = ((int)f3) & 255;
        qw[tid + 256 * i] = b0 | (b1 << 8) | (b2 << 16) | (b3 << 24);
    }
}

// ---------------------------------------------------------------------------
// Kernel 2: pack int32 weight buffer -> int8
// ---------------------------------------------------------------------------
__global__ __launch_bounds__(256) void pack_w(const int* __restrict__ w,
                                              int8_t* __restrict__ w8) {
    const int idx = blockIdx.x * 256 + threadIdx.x;
    const int4 v = reinterpret_cast<const int4*>(w)[idx];
    int packed = (v.x & 255) | ((v.y & 255) << 8) | ((v.z & 255) << 16) | ((v.w & 255) << 24);
    reinterpret_cast<int*>(w8)[idx] = packed;
}

// ---------------------------------------------------------------------------
// Kernel 3: int8 GEMM, m201-style 8-phase-equivalent schedule.
// 256x256 tile, BK=128 i8 (128 B rows, byte-identical geometry to m201 bf16),
// 8 waves (2Mx4N), 2-deep LDS dbuf (128 KB), 4 phases/K-tile x 16 MFMA,
// derived counted vmcnt (never drains in steady state), T2 XOR swizzle,
// T5 setprio.
//
// Staging: tile = 8 chunks of 64 rows x 128 B (A0..A3, B0..B3), 1 GLL each
// (512 thr x 16 B). Issue order during tile t (for t+1):
//   ph0: A0,A2,B0   ph1: B1,B2,B3   ph2: A1,A3   ph3: -
// Need-by: {A0,A2,B0..B3}(t+1) by ph0 of t+1 -> end-ph3 vmcnt(2) (first 6
// of the 8 outstanding). {A1,A3}(t) by ph2 of t -> end-ph0 vmcnt(3)
// (outstanding = A1,A3(t) + 3 just-issued). Leads >= 2 phases. Drain-0 only
// in the last tile's ph0.
//
// LDS swizzle (both-sides involution): LDS[row][slot] holds global granule
// slot ^ (row&7); staged by pre-swizzling the per-lane GLOBAL address
// (dest stays linear, rule 21); read at slot = kcol ^ (row&7). ds_read_b128
// per 16-lane group spreads across all 8 slot positions -> 2-way max = free.
// ---------------------------------------------------------------------------
constexpr int BM = 256, BN = 256, BKB = 128;
constexpr int NT = K_DIM / BKB;    // 32 K-tiles

#define GLL(src, dst)                                                          \
    __builtin_amdgcn_global_load_lds(                                          \
        (const __attribute__((address_space(1))) unsigned int*)(src),          \
        (__attribute__((address_space(3))) unsigned int*)(dst), 16, 0, 0)

#define MFMA_I8(a, b, c) __builtin_amdgcn_mfma_i32_16x16x64_i8((a), (b), (c), 0, 0, 0)

__global__ __launch_bounds__(512, 2) void w8a8_gemm256(
        const int8_t* __restrict__ A, const int8_t* __restrict__ B,
        const float* __restrict__ asc, const float* __restrict__ wsc,
        float* __restrict__ C, int M) {
    extern __shared__ int8_t lds[];           // 128 KB: A dbuf @0, B dbuf @65536

    const int tid  = threadIdx.x;
    const int lane = tid & 63;
    const int wave = tid >> 6;

    // XCD-aware bijective swizzle (nwg = 512, divisible by 8)
    const int nwg = gridDim.x;
    const int bid = blockIdx.x;
    const int swz = (bid & 7) * (nwg >> 3) + (bid >> 3);
    const int NB  = N_DIM / BN;               // 16
    const int brow = (swz / NB) * BM;
    const int bcol = (swz % NB) * BN;

    const int wm = wave >> 2;                 // 0..1
    const int wn = wave & 3;                  // 0..3
    const int l15 = lane & 15;
    const int ls  = lane >> 4;

    // ---- staging addresses (per-lane pre-swizzled GLOBAL source) ----
    const int rowin = tid >> 3;                         // 0..63 within chunk
    const int gsl   = ((tid & 7) ^ (rowin & 7)) * 16;   // swizzled granule
    const int8_t* gA = A + (size_t)(brow + rowin) * K_DIM + gsl;
    const int8_t* gB = B + (size_t)(bcol + rowin) * K_DIM + gsl;
    const size_t chunk_g = (size_t)64 * K_DIM;          // +64 rows in global
    const int segb = wave * 1024;                       // wave-uniform LDS base

    // ---- compute-side swizzled LDS offsets ----
    const int sbase = ((ls ^ (l15 & 7)) * 16);          // kh=0 slot bytes
    const int offA0 = (wm * 128 + l15) * BKB + sbase;   // + mi*2048, ^ kh*64
    const int offB0 = (wn * 64  + l15) * BKB + sbase;   // + ni*2048, ^ kh*64

    int32x4 acc[8][4];
#pragma unroll
    for (int i = 0; i < 8; ++i)
#pragma unroll
        for (int j = 0; j < 4; ++j) acc[i][j] = (int32x4){0, 0, 0, 0};

    // ---- prologue: stage tile 0 fully ----
#pragma unroll
    for (int c = 0; c < 4; ++c) {
        GLL(gA + c * chunk_g, lds + c * 8192 + segb);
        GLL(gB + c * chunk_g, lds + 65536 + c * 8192 + segb);
    }
    asm volatile("s_waitcnt vmcnt(0)" ::: "memory");
    __builtin_amdgcn_s_barrier();

    int32x4 af[8], bf01[4], bf23[4];

    for (int t = 0; t < NT; ++t) {
        const int8_t* Ab = lds + (t & 1) * 32768;
        const int8_t* Bb = lds + 65536 + (t & 1) * 32768;
        const int  p1   = (t + 1) & 1;
        const bool pf   = (t + 1 < NT);
        const size_t kk = (size_t)(t + 1) * BKB;
        int8_t* dA = lds + p1 * 32768;
        int8_t* dB = lds + 65536 + p1 * 32768;

        // ======== phase 0: GLL {A0,A2,B0}; read A[m0-3]x2kh + B[n0-1]x2kh
        if (pf) {
            GLL(gA + kk,               dA + segb);            // A0
            GLL(gA + kk + 2 * chunk_g, dA + 16384 + segb);    // A2
            GLL(gB + kk,               dB + segb);            // B0
        }
#pragma unroll
        for (int mi = 0; mi < 4; ++mi) {
            af[2 * mi]     = *(const int32x4*)(Ab + ((offA0 + mi * 2048)));
            af[2 * mi + 1] = *(const int32x4*)(Ab + ((offA0 + mi * 2048) ^ 64));
        }
#pragma unroll
        for (int ni = 0; ni < 2; ++ni) {
            bf01[2 * ni]     = *(const int32x4*)(Bb + ((offB0 + ni * 2048)));
            bf01[2 * ni + 1] = *(const int32x4*)(Bb + ((offB0 + ni * 2048) ^ 64));
        }
        __builtin_amdgcn_s_barrier();
        asm volatile("s_waitcnt lgkmcnt(0)" ::: "memory");
        __builtin_amdgcn_s_setprio(1);
#pragma unroll
        for (int mi = 0; mi < 4; ++mi)
#pragma unroll
            for (int ni = 0; ni < 2; ++ni)
#pragma unroll
                for (int kh = 0; kh < 2; ++kh)
                    acc[mi][ni] = MFMA_I8(af[2 * mi + kh], bf01[2 * ni + kh], acc[mi][ni]);
        __builtin_amdgcn_s_setprio(0);
        if (t < NT - 1) asm volatile("s_waitcnt vmcnt(3)" ::: "memory");
        else            asm volatile("s_waitcnt vmcnt(0)" ::: "memory");
        __builtin_amdgcn_s_barrier();

        // ======== phase 1: GLL {B1,B2,B3}; read B[n2-3]x2kh
        if (pf) {
            GLL(gB + kk + 1 * chunk_g, dB + 8192 + segb);     // B1
            GLL(gB + kk + 2 * chunk_g, dB + 16384 + segb);    // B2
            GLL(gB + kk + 3 * chunk_g, dB + 24576 + segb);    // B3
        }
#pragma unroll
        for (int ni = 0; ni < 2; ++ni) {
            bf23[2 * ni]     = *(const int32x4*)(Bb + ((offB0 + (ni + 2) * 2048)));
            bf23[2 * ni + 1] = *(const int32x4*)(Bb + ((offB0 + (ni + 2) * 2048) ^ 64));
        }
        __builtin_amdgcn_s_barrier();
        asm volatile("s_waitcnt lgkmcnt(0)" ::: "memory");
        __builtin_amdgcn_s_setprio(1);
#pragma unroll
        for (int mi = 0; mi < 4; ++mi)
#pragma unroll
            for (int ni = 0; ni < 2; ++ni)
#pragma unroll
                for (int kh = 0; kh < 2; ++kh)
                    acc[mi][ni + 2] = MFMA_I8(af[2 * mi + kh], bf23[2 * ni + kh], acc[mi][ni + 2]);
        __builtin_amdgcn_s_setprio(0);
        __builtin_amdgcn_s_barrier();

        // ======== phase 2: GLL {A1,A3}; read A[m4-7]x2kh
        if (pf) {
            GLL(gA + kk + 1 * chunk_g, dA + 8192 + segb);     // A1
            GLL(gA + kk + 3 * chunk_g, dA + 24576 + segb);    // A3
        }
#pragma unroll
        for (int mi = 0; mi < 4; ++mi) {
            af[2 * mi]     = *(const int32x4*)(Ab + ((offA0 + (mi + 4) * 2048)));
            af[2 * mi + 1] = *(const int32x4*)(Ab + ((offA0 + (mi + 4) * 2048) ^ 64));
        }
        __builtin_amdgcn_s_barrier();
        asm volatile("s_waitcnt lgkmcnt(0)" ::: "memory");
        __builtin_amdgcn_s_setprio(1);
#pragma unroll
        for (int mi = 0; mi < 4; ++mi)
#pragma unroll
            for (int ni = 0; ni < 2; ++ni)
#pragma unroll
                for (int kh = 0; kh < 2; ++kh)
                    acc[mi + 4][ni + 2] = MFMA_I8(af[2 * mi + kh], bf23[2 * ni + kh], acc[mi + 4][ni + 2]);
        __builtin_amdgcn_s_setprio(0);
        __builtin_amdgcn_s_barrier();

        // ======== phase 3: no GLL, no reads; MFMA m4-7 x n0-1
        __builtin_amdgcn_s_setprio(1);
#pragma unroll
        for (int mi = 0; mi < 4; ++mi)
#pragma unroll
            for (int ni = 0; ni < 2; ++ni)
#pragma unroll
                for (int kh = 0; kh < 2; ++kh)
                    acc[mi + 4][ni] = MFMA_I8(af[2 * mi + kh], bf01[2 * ni + kh], acc[mi + 4][ni]);
        __builtin_amdgcn_s_setprio(0);
        asm volatile("s_waitcnt vmcnt(2)" ::: "memory");   // first 6 of t+1 landed
        __builtin_amdgcn_s_barrier();
    }

    // ---- epilogue: dequant + fp16-round; C/D: col=lane&15, row=(lane>>4)*4+reg
    const int c0  = lane & 15;
    const int rr0 = (lane >> 4) * 4;
#pragma unroll
    for (int ni = 0; ni < 4; ++ni) {
        const int col = bcol + wn * 64 + ni * 16 + c0;
        const float ws = wsc[col];
#pragma unroll
        for (int mi = 0; mi < 8; ++mi) {
            const int rowb = brow + wm * 128 + mi * 16 + rr0;
#pragma unroll
            for (int r = 0; r < 4; ++r) {
                const int row = rowb + r;
                float o = (float)acc[mi][ni][r] * asc[row] * ws;
                o = (float)(_Float16)o;   // emulate reference's fp16 cast
                C[(size_t)row * N_DIM + col] = o;
            }
        }
    }
}

// ---------------------------------------------------------------------------
extern "C" void kernel_launch(void* const* d_in, const int* in_sizes, int n_in,
                              void* d_out, int out_size, void* d_ws, size_t ws_size,
                              hipStream_t stream) {
    const float* x   = (const float*)d_in[0];   // [M][K], fp16-valued f32
    const int*   w   = (const int*)d_in[1];     // [N][K] int32 (int8-valued)
    const float* wsc = (const float*)d_in[2];   // [N]
    float* out = (float*)d_out;                 // [M][N] (fp16-valued f32)

    const int K = K_DIM;
    const int M = in_sizes[0] / K;              // 8192
    const int N = N_DIM;

    int8_t* q   = (int8_t*)d_ws;                               // M*K  = 32 MB
    int8_t* w8  = (int8_t*)d_ws + (size_t)M * K;               // N*K  = 16 MB
    float*  asc = (float*)((char*)d_ws + (size_t)M * K + (size_t)N * K);

    quant_rows<<<M, 256, 0, stream>>>(x, q, asc);
    pack_w<<<(N * (K / 4)) / 256, 256, 0, stream>>>(w, w8);
    const int grid = (M / BM) * (N / BN);       // 512
    w8a8_gemm256<<<grid, 512, 131072, stream>>>(q, w8, asc, wsc, out, M);
}

// Round 6
// 182.536 us; speedup vs baseline: 1.9988x; 1.0199x over previous
//
#include <hip/hip_runtime.h>
#include <stdint.h>

typedef int int32x4 __attribute__((ext_vector_type(4)));

constexpr int K_DIM = 4096;   // D_IN
constexpr int N_DIM = 4096;   // D_OUT
constexpr float QMAXF = 127.0f;

// ---------------------------------------------------------------------------
// Kernel 1: per-token dynamic absmax quantization
// ---------------------------------------------------------------------------
__global__ __launch_bounds__(256) void quant_rows(const float* __restrict__ x,
                                                  int8_t* __restrict__ q,
                                                  float* __restrict__ scales) {
    const int row = blockIdx.x;
    const int tid = threadIdx.x;
    const size_t base = (size_t)row * K_DIM;

    const float4* xv = reinterpret_cast<const float4*>(x + base);
    float4 v[4];
#pragma unroll
    for (int i = 0; i < 4; ++i) v[i] = xv[tid + 256 * i];

    float m = 0.0f;
#pragma unroll
    for (int i = 0; i < 4; ++i)
        m = fmaxf(m, fmaxf(fmaxf(fabsf(v[i].x), fabsf(v[i].y)),
                           fmaxf(fabsf(v[i].z), fabsf(v[i].w))));
#pragma unroll
    for (int off = 32; off > 0; off >>= 1) m = fmaxf(m, __shfl_xor(m, off));

    __shared__ float wmax[4];
    if ((tid & 63) == 0) wmax[tid >> 6] = m;
    __syncthreads();
    const float am = fmaxf(fmaxf(wmax[0], wmax[1]), fmaxf(wmax[2], wmax[3]));
    const float scale = fmaxf(am * (1.0f / 127.0f), 1e-8f);
    if (tid == 0) scales[row] = scale;
    const float inv = 1.0f / scale;

    int* qw = reinterpret_cast<int*>(q + base);
#pragma unroll
    for (int i = 0; i < 4; ++i) {
        float f0 = fminf(QMAXF, fmaxf(-QMAXF, rintf(v[i].x * inv)));
        float f1 = fminf(QMAXF, fmaxf(-QMAXF, rintf(v[i].y * inv)));
        float f2 = fminf(QMAXF, fmaxf(-QMAXF, rintf(v[i].z * inv)));
        float f3 = fminf(QMAXF, fmaxf(-QMAXF, rintf(v[i].w * inv)));
        int b0 = ((int)f0) & 255, b1 = ((int)f1) & 255;
        int b2 = ((int)f2) & 255, b3 = ((int)f3) & 255;
        qw[tid + 256 * i] = b0 | (b1 << 8) | (b2 << 16) | (b3 << 24);
    }
}

// ---------------------------------------------------------------------------
// Kernel 2: pack int32 weight buffer -> int8
// ---------------------------------------------------------------------------
__global__ __launch_bounds__(256) void pack_w(const int* __restrict__ w,
                                              int8_t* __restrict__ w8) {
    const int idx = blockIdx.x * 256 + threadIdx.x;
    const int4 v = reinterpret_cast<const int4*>(w)[idx];
    int packed = (v.x & 255) | ((v.y & 255) << 8) | ((v.z & 255) << 16) | ((v.w & 255) << 24);
    reinterpret_cast<int*>(w8)[idx] = packed;
}

// ---------------------------------------------------------------------------
// Kernel 3: int8 GEMM, barrier-free mi-phase schedule.
// 256x256 tile, BK=128, 8 waves (2Mx4N), 2-deep LDS dbuf (128 KB).
// Per K-tile: 2 barriers total. Tile body = read all B frags (8 ds) + A0,A1;
// then 8 phases: {issue A[mi+2] reads | GLL B-batch at mi==4 | lgkmcnt gate |
// 8 MFMA on A[mi] x B[0..3] x kh0..1}. Waves slip freely between barriers ->
// LDS pipe overlaps MFMA pipe across waves.
//
// GLL ledger: A-batch(t+1) x4 issued at tile-t top (after B1 WAR fence);
// B-batch(t+1) x4 at mi==4. Entry gate of tile t: after issuing A(t+1),
// vmcnt(4) => tile t's 8 oldest landed, t+1's A still in flight (no drain);
// barrier B2 makes it block-wide. Issue-to-gate distance ~1 tile (>2000 cyc)
// >> HBM latency, so even the tail vmcnt(0) is cheap.
//
// lgkm ledger (per wave): after tile-top reads (12) + phase-mi issue (2):
// need oldest {B(8)+A[mi]} done -> lgkmcnt(4) phases 0..5, (2) at 6, (0) at 7.
//
// LDS swizzle (both-sides involution, rule 21): row r granule g stored at
// slot g^(r&7); staged via pre-swizzled per-lane GLOBAL address (linear LDS
// dest); read at slot kcol^(r&7). Verified rounds 4-5 (bank conflicts = 0).
// ---------------------------------------------------------------------------
constexpr int BM = 256, BN = 256, BKB = 128;
constexpr int NT = K_DIM / BKB;    // 32 K-tiles

#define GLL(src, dst)                                                          \
    __builtin_amdgcn_global_load_lds(                                          \
        (const __attribute__((address_space(1))) unsigned int*)(src),          \
        (__attribute__((address_space(3))) unsigned int*)(dst), 16, 0, 0)

#define MFMA_I8(a, b, c) __builtin_amdgcn_mfma_i32_16x16x64_i8((a), (b), (c), 0, 0, 0)

__global__ __launch_bounds__(512, 2) void w8a8_gemm256(
        const int8_t* __restrict__ A, const int8_t* __restrict__ B,
        const float* __restrict__ asc, const float* __restrict__ wsc,
        float* __restrict__ C, int M) {
    extern __shared__ int8_t lds[];           // 128 KB: A dbuf @0, B dbuf @65536

    const int tid  = threadIdx.x;
    const int lane = tid & 63;
    const int wave = tid >> 6;

    // XCD-aware bijective swizzle (nwg = 512, divisible by 8)
    const int nwg = gridDim.x;
    const int bid = blockIdx.x;
    const int swz = (bid & 7) * (nwg >> 3) + (bid >> 3);
    const int NB  = N_DIM / BN;               // 16
    const int brow = (swz / NB) * BM;
    const int bcol = (swz % NB) * BN;

    const int wm = wave >> 2;                 // 0..1
    const int wn = wave & 3;                  // 0..3
    const int l15 = lane & 15;
    const int ls  = lane >> 4;

    // ---- staging addresses (per-lane pre-swizzled GLOBAL source) ----
    const int rowin = tid >> 3;                         // 0..63 within chunk
    const int gsl   = ((tid & 7) ^ (rowin & 7)) * 16;   // swizzled granule
    const int8_t* gA = A + (size_t)(brow + rowin) * K_DIM + gsl;
    const int8_t* gB = B + (size_t)(bcol + rowin) * K_DIM + gsl;
    const size_t chunk_g = (size_t)64 * K_DIM;          // +64 rows in global
    const int segb = wave * 1024;                       // wave-uniform LDS base

    // ---- compute-side swizzled LDS offsets ----
    const int sbase = ((ls ^ (l15 & 7)) * 16);          // kh=0 slot bytes
    const int offA0 = (wm * 128 + l15) * BKB + sbase;   // + mi*2048, ^64 for kh=1
    const int offB0 = (wn * 64  + l15) * BKB + sbase;   // + ni*2048, ^64 for kh=1

    int32x4 acc[8][4];
#pragma unroll
    for (int i = 0; i < 8; ++i)
#pragma unroll
        for (int j = 0; j < 4; ++j) acc[i][j] = (int32x4){0, 0, 0, 0};

    // ---- prologue: stage tile 0 fully (A-batch then B-batch) ----
#pragma unroll
    for (int c = 0; c < 4; ++c) GLL(gA + c * chunk_g, lds + c * 8192 + segb);
#pragma unroll
    for (int c = 0; c < 4; ++c) GLL(gB + c * chunk_g, lds + 65536 + c * 8192 + segb);

    int32x4 bf[4][2];
    int32x4 afr[3][2];

    for (int t = 0; t < NT; ++t) {
        const int8_t* Ab = lds + (t & 1) * 32768;
        const int8_t* Bb = lds + 65536 + (t & 1) * 32768;
        int8_t* dA = lds + ((t + 1) & 1) * 32768;
        int8_t* dB = lds + 65536 + ((t + 1) & 1) * 32768;
        const bool pf = (t + 1 < NT);
        const size_t kk = (size_t)(t + 1) * BKB;

        // B1: WAR fence — all waves done reading buf[(t+1)&1] (= tile t-1)
        __builtin_amdgcn_s_barrier();
        if (pf) {
#pragma unroll
            for (int c = 0; c < 4; ++c) GLL(gA + kk + c * chunk_g, dA + c * 8192 + segb);
            asm volatile("s_waitcnt vmcnt(4)" ::: "memory");   // tile t landed
        } else {
            asm volatile("s_waitcnt vmcnt(0)" ::: "memory");
        }
        // B2: staging visibility block-wide
        __builtin_amdgcn_s_barrier();

        // tile-top reads: all B frags (8) + A0 (2) + A1 (2)
#pragma unroll
        for (int ni = 0; ni < 4; ++ni) {
            bf[ni][0] = *(const int32x4*)(Bb + ((offB0 + ni * 2048)));
            bf[ni][1] = *(const int32x4*)(Bb + ((offB0 + ni * 2048) ^ 64));
        }
#pragma unroll
        for (int mi = 0; mi < 2; ++mi) {
            afr[mi][0] = *(const int32x4*)(Ab + ((offA0 + mi * 2048)));
            afr[mi][1] = *(const int32x4*)(Ab + ((offA0 + mi * 2048) ^ 64));
        }

        // 8 mi-phases, no barriers
#pragma unroll
        for (int mi = 0; mi < 8; ++mi) {
            if (mi < 6) {
                const int s = (mi + 2) % 3;
                afr[s][0] = *(const int32x4*)(Ab + ((offA0 + (mi + 2) * 2048)));
                afr[s][1] = *(const int32x4*)(Ab + ((offA0 + (mi + 2) * 2048) ^ 64));
            }
            if (mi == 4 && pf) {
#pragma unroll
                for (int c = 0; c < 4; ++c)
                    GLL(gB + kk + c * chunk_g, dB + c * 8192 + segb);
            }
            if (mi < 6)      asm volatile("s_waitcnt lgkmcnt(4)" ::: "memory");
            else if (mi == 6) asm volatile("s_waitcnt lgkmcnt(2)" ::: "memory");
            else              asm volatile("s_waitcnt lgkmcnt(0)" ::: "memory");
            __builtin_amdgcn_sched_barrier(0);   // rule 18: keep MFMA below wait

            const int cs = mi % 3;
            __builtin_amdgcn_s_setprio(1);
#pragma unroll
            for (int ni = 0; ni < 4; ++ni) {
                acc[mi][ni] = MFMA_I8(afr[cs][0], bf[ni][0], acc[mi][ni]);
                acc[mi][ni] = MFMA_I8(afr[cs][1], bf[ni][1], acc[mi][ni]);
            }
            __builtin_amdgcn_s_setprio(0);
        }
    }

    // ---- epilogue: dequant + fp16-round; C/D: col=lane&15, row=(lane>>4)*4+reg
    const int c0  = lane & 15;
    const int rr0 = (lane >> 4) * 4;
#pragma unroll
    for (int ni = 0; ni < 4; ++ni) {
        const int col = bcol + wn * 64 + ni * 16 + c0;
        const float ws = wsc[col];
#pragma unroll
        for (int mi = 0; mi < 8; ++mi) {
            const int rowb = brow + wm * 128 + mi * 16 + rr0;
#pragma unroll
            for (int r = 0; r < 4; ++r) {
                const int row = rowb + r;
                float o = (float)acc[mi][ni][r] * asc[row] * ws;
                o = (float)(_Float16)o;   // emulate reference's fp16 cast
                C[(size_t)row * N_DIM + col] = o;
            }
        }
    }
}

// ---------------------------------------------------------------------------
extern "C" void kernel_launch(void* const* d_in, const int* in_sizes, int n_in,
                              void* d_out, int out_size, void* d_ws, size_t ws_size,
                              hipStream_t stream) {
    const float* x   = (const float*)d_in[0];   // [M][K], fp16-valued f32
    const int*   w   = (const int*)d_in[1];     // [N][K] int32 (int8-valued)
    const float* wsc = (const float*)d_in[2];   // [N]
    float* out = (float*)d_out;                 // [M][N] (fp16-valued f32)

    const int K = K_DIM;
    const int M = in_sizes[0] / K;              // 8192
    const int N = N_DIM;

    int8_t* q   = (int8_t*)d_ws;                               // M*K  = 32 MB
    int8_t* w8  = (int8_t*)d_ws + (size_t)M * K;               // N*K  = 16 MB
    float*  asc = (float*)((char*)d_ws + (size_t)M * K + (size_t)N * K);

    quant_rows<<<M, 256, 0, stream>>>(x, q, asc);
    pack_w<<<(N * (K / 4)) / 256, 256, 0, stream>>>(w, w8);
    const int grid = (M / BM) * (N / BN);       // 512
    w8a8_gemm256<<<grid, 512, 131072, stream>>>(q, w8, asc, wsc, out, M);
}